// Round 8
// baseline (314.278 us; speedup 1.0000x reference)
//
#include <hip/hip_runtime.h>

#define BS 256
#define NS 24   // candidate slots: 4 c1-corners, 4 c2-corners, 16 "intersections"

__device__ __forceinline__ float rcpf(float x) { return __builtin_amdgcn_rcpf(x); }

// One-instruction pack: round-nearest(clamp(x,-1,1)*32767) -> i16, y in high16.
__device__ __forceinline__ unsigned pk16(float x, float y) {
    unsigned r;
    asm("v_cvt_pknorm_i16_f32 %0, %1, %2" : "=v"(r) : "v"(x), "v"(y));
    return r;
}

// Key+payload compare-exchange, literal indices only (runtime indices ->
// scratch). 4 ops: key min/max + 2 payload cndmasks. Stable on key ties
// (sw false -> no swap). Payload-in-register is what deletes the 24KB LDS
// buffer (occupancy 24 -> 32 waves/CU); gather-by-runtime-index would need
// LDS, a comparator network does not.
#define CSWAPKP(A, B) do {                                        \
    const unsigned ka_ = key[A], kb_ = key[B];                    \
    const unsigned pa_ = pay[A], pb_ = pay[B];                    \
    const bool sw_ = (kb_ < ka_);                                 \
    key[A] = sw_ ? kb_ : ka_;  key[B] = sw_ ? ka_ : kb_;          \
    pay[A] = sw_ ? pb_ : pa_;  pay[B] = sw_ ? pa_ : pb_;          \
} while (0)

// (x,y) compare-exchange by x, literal indices
#define CSW2(x, y, I, J) do {                                     \
    const bool sw_ = (x[J] < x[I]);                               \
    const float xi_ = x[I], xj_ = x[J], yi_ = y[I], yj_ = y[J];   \
    x[I] = sw_ ? xj_ : xi_;  x[J] = sw_ ? xi_ : xj_;              \
    y[I] = sw_ ? yj_ : yi_;  y[J] = sw_ ? yi_ : yj_;              \
} while (0)

// NOTE (R4): BS=128 regressed 1.87x (2-wave blocks can't populate the CU).
// Keep BS=256. Second bound = 8 waves/SIMD pins VGPR<=64: required, since
// 65..128 VGPR would halve waves/CU to 16 and negate the LDS win.
__global__ __launch_bounds__(BS, 8)
void fpdiou_kernel(const float* __restrict__ pred, const float* __restrict__ tgt,
                   float* __restrict__ out, int n, float inv_n)
{
    __shared__ float s_red[BS / 64];

    const int tid = threadIdx.x;
    const int i = blockIdx.x * BS + tid;
    float loss = 0.f;

    if (i < n) {
        const float* pp = pred + (size_t)i * 5;
        const float* gg = tgt  + (size_t)i * 5;
        const float p0 = pp[0], p1 = pp[1], pw = pp[2], ph = pp[3], pa = pp[4];
        const float g0 = gg[0], g1 = gg[1], gw = gg[2], gh = gg[3], ga = gg[4];

        const float s1 = __sinf(pa), co1 = __cosf(pa);
        const float s2 = __sinf(ga), co2 = __cosf(ga);

        const float DX[4] = {0.5f, -0.5f, -0.5f, 0.5f};
        const float DY[4] = {0.5f,  0.5f, -0.5f, -0.5f};
        float c1x[4], c1y[4], c2x[4], c2y[4];
#pragma unroll
        for (int q = 0; q < 4; q++) {
            float dx = DX[q] * pw, dy = DY[q] * ph;
            c1x[q] = dx * co1 - dy * s1 + p0;
            c1y[q] = dx * s1 + dy * co1 + p1;
            dx = DX[q] * gw; dy = DY[q] * gh;
            c2x[q] = dx * co2 - dy * s2 + g0;
            c2y[q] = dx * s2 + dy * co2 + g1;
        }

        const float PKS = 128.f / 32767.f;   // pknorm scale: quantum = 1/128 px

        // ---- FPDIoU distance term: 5-comparator sort-by-x networks ----
        float res;
        {
            float px_[4] = {c1x[0], c1x[1], c1x[2], c1x[3]};
            float py_[4] = {c1y[0], c1y[1], c1y[2], c1y[3]};
            float gx_[4] = {c2x[0], c2x[1], c2x[2], c2x[3]};
            float gy_[4] = {c2y[0], c2y[1], c2y[2], c2y[3]};
            CSW2(px_, py_, 0, 1); CSW2(px_, py_, 2, 3);
            CSW2(px_, py_, 0, 2); CSW2(px_, py_, 1, 3); CSW2(px_, py_, 1, 2);
            CSW2(gx_, gy_, 0, 1); CSW2(gx_, gy_, 2, 3);
            CSW2(gx_, gy_, 0, 2); CSW2(gx_, gy_, 1, 3); CSW2(gx_, gy_, 1, 2);
            const float d0 = gx_[0] - px_[0];
            float d = 2.f * d0 * d0;
#pragma unroll
            for (int q = 1; q < 4; q++) {
                const float dxq = px_[q] - gx_[q];
                const float dyq = py_[q] - gy_[q];
                d += dxq * dxq + dyq * dyq;
            }
            res = d * (1.f / 4194304.f);
        }

        // ---- fill 24 slots: packed coords -> REGISTERS; validity bitmask ----
        unsigned pay[NS];
        unsigned vm = 0;
        float sx = 0.f, sy = 0.f;
        const float e = 1e-6f;

        // slots 0..3: c1 corners inside box2 (division-free threshold form)
        {
            const float ax = c2x[0], ay = c2y[0];
            const float abx = c2x[1] - ax, aby = c2y[1] - ay;
            const float adx = c2x[3] - ax, ady = c2y[3] - ay;
            const float dab = abx * abx + aby * aby;
            const float dad = adx * adx + ady * ady;
            const float lo_ab = -e * dab, hi_ab = (1.f + e) * dab;
            const float lo_ad = -e * dad, hi_ad = (1.f + e) * dad;
#pragma unroll
            for (int q = 0; q < 4; q++) {
                const float amx = c1x[q] - ax, amy = c1y[q] - ay;
                const float dot_ab = abx * amx + aby * amy;
                const float dot_ad = adx * amx + ady * amy;
                const bool m = (dot_ab > lo_ab) & (dot_ab < hi_ab)
                             & (dot_ad > lo_ad) & (dot_ad < hi_ad);
                pay[q] = pk16((c1x[q] - p0) * PKS, (c1y[q] - p1) * PKS);
                if (m) { vm |= 1u << q; sx += c1x[q]; sy += c1y[q]; }
            }
        }
        // slots 4..7: c2 corners inside box1
        {
            const float ax = c1x[0], ay = c1y[0];
            const float abx = c1x[1] - ax, aby = c1y[1] - ay;
            const float adx = c1x[3] - ax, ady = c1y[3] - ay;
            const float dab = abx * abx + aby * aby;
            const float dad = adx * adx + ady * ady;
            const float lo_ab = -e * dab, hi_ab = (1.f + e) * dab;
            const float lo_ad = -e * dad, hi_ad = (1.f + e) * dad;
#pragma unroll
            for (int q = 0; q < 4; q++) {
                const float amx = c2x[q] - ax, amy = c2y[q] - ay;
                const float dot_ab = abx * amx + aby * amy;
                const float dot_ad = adx * amx + ady * amy;
                const bool m = (dot_ab > lo_ab) & (dot_ab < hi_ab)
                             & (dot_ad > lo_ad) & (dot_ad < hi_ad);
                pay[4 + q] = pk16((c2x[q] - p0) * PKS, (c2y[q] - p1) * PKS);
                if (m) { vm |= 1u << (4 + q); sx += c2x[q]; sy += c2y[q]; }
            }
        }
        // slots 8..23: reference's quirky "intersections" (the reference's u has
        // a sign flip vs true segment params -- it accepts crossings with the
        // BACKWARD extension of c2 edges and rejects true crossings. This mask
        // emulates that exactly; do NOT replace with true geometry.)
        // ix,iy packed immediately -> no iix/iiy register arrays (VGPR budget).
#pragma unroll
        for (int a = 0; a < 4; a++) {
            const float x1 = c1x[a], y1 = c1y[a];
            const float ex = c1x[(a + 1) & 3] - x1, ey = c1y[(a + 1) & 3] - y1;
#pragma unroll
            for (int b = 0; b < 4; b++) {
                const float x3 = c2x[b], y3 = c2y[b];
                const float fx = c2x[(b + 1) & 3] - x3, fy = c2y[(b + 1) & 3] - y3;
                const float num = fy * ex - fx * ey;
                const float dx13 = x1 - x3, dy13 = y1 - y3;
                const float den_t = fx * dy13 - fy * dx13;
                const float den_u = ex * dy13 - ey * dx13;
                // t=den_t/num in (0,1) <=> den_t*num>0 && |den_t|<|num|;
                // u=-den_u/num in (0,1) <=> den_u*num<0 && |den_u|<|num|;
                // num==0 -> products +-0 -> strict cmps false (ref's t=-1 case).
                const bool m = (den_t * num > 0.f) & (fabsf(den_t) < fabsf(num))
                             & (den_u * num < 0.f) & (fabsf(den_u) < fabsf(num));
                const float t2 = den_t * rcpf(num + 1e-8f);   // reference quirk
                const float ix = fmaf(t2, ex, x1), iy = fmaf(t2, ey, y1);
                const int s = 8 + a * 4 + b;
                pay[s] = pk16((ix - p0) * PKS, (iy - p1) * PKS);
                if (m) { vm |= 1u << s; sx += ix; sy += iy; }
            }
        }

        // ---- keys from QUANTIZED payload (quantum units; angle order is ----
        // scale-invariant). ang = copysign(1 - dx/(|dx|+|dy|), dy) in [-2,2],
        // +4 -> [2,6] all positive => IEEE bits sort ascending as u32 directly.
        // Invalid -> 1e9f sorts after all valid. dx=dy=0 -> NaN key: sorts
        // last, fails the gather validity test => dropped (k<=2 cases give
        // area 0 under any order; k>=3 exact-coincidence is measure-zero).
        const int kq = __popc(vm);
        const float kf = (float)(kq > 0 ? kq : 1);
        const float rkf = rcpf(kf);
        const float oxq = (sx * rkf - p0) * 128.f;   // centroid, quantum units
        const float oyq = (sy * rkf - p1) * 128.f;
        unsigned key[NS];
#pragma unroll
        for (int s = 0; s < NS; s++) {
            const unsigned w = pay[s];
            const float dx = (float)((int)(w << 16) >> 16) - oxq;
            const float dy = (float)((int)w >> 16) - oyq;
            const float sa = fabsf(dx) + fabsf(dy);
            const float m1 = fmaf(-dx, rcpf(sa), 1.f);       // [0,2]
            float a4 = copysignf(m1, dy) + 4.f;              // [2,6]
            a4 = ((vm >> s) & 1u) ? a4 : 1e9f;               // invalid -> back
            key[s] = (__float_as_uint(a4) & 0xFFFFFFE0u) | (unsigned)s;
        }

        // ---- Batcher merge-exchange network, n=24 (127 comparators), ----
        // key + payload carried in registers.
        // p=16
        CSWAPKP(0,16); CSWAPKP(1,17); CSWAPKP(2,18); CSWAPKP(3,19);
        CSWAPKP(4,20); CSWAPKP(5,21); CSWAPKP(6,22); CSWAPKP(7,23);
        // p=8
        CSWAPKP(0,8);  CSWAPKP(1,9);  CSWAPKP(2,10); CSWAPKP(3,11);
        CSWAPKP(4,12); CSWAPKP(5,13); CSWAPKP(6,14); CSWAPKP(7,15);
        CSWAPKP(8,16); CSWAPKP(9,17); CSWAPKP(10,18); CSWAPKP(11,19);
        CSWAPKP(12,20); CSWAPKP(13,21); CSWAPKP(14,22); CSWAPKP(15,23);
        // p=4
        CSWAPKP(0,4);  CSWAPKP(1,5);  CSWAPKP(2,6);  CSWAPKP(3,7);
        CSWAPKP(8,12); CSWAPKP(9,13); CSWAPKP(10,14); CSWAPKP(11,15);
        CSWAPKP(16,20); CSWAPKP(17,21); CSWAPKP(18,22); CSWAPKP(19,23);
        CSWAPKP(4,16); CSWAPKP(5,17); CSWAPKP(6,18); CSWAPKP(7,19);
        CSWAPKP(4,8);  CSWAPKP(5,9);  CSWAPKP(6,10); CSWAPKP(7,11);
        CSWAPKP(12,16); CSWAPKP(13,17); CSWAPKP(14,18); CSWAPKP(15,19);
        // p=2
        CSWAPKP(0,2);  CSWAPKP(1,3);  CSWAPKP(4,6);  CSWAPKP(5,7);
        CSWAPKP(8,10); CSWAPKP(9,11); CSWAPKP(12,14); CSWAPKP(13,15);
        CSWAPKP(16,18); CSWAPKP(17,19); CSWAPKP(20,22); CSWAPKP(21,23);
        CSWAPKP(2,16); CSWAPKP(3,17); CSWAPKP(6,20); CSWAPKP(7,21);
        CSWAPKP(2,8);  CSWAPKP(3,9);  CSWAPKP(6,12); CSWAPKP(7,13);
        CSWAPKP(10,16); CSWAPKP(11,17); CSWAPKP(14,20); CSWAPKP(15,21);
        CSWAPKP(2,4);  CSWAPKP(3,5);  CSWAPKP(6,8);  CSWAPKP(7,9);
        CSWAPKP(10,12); CSWAPKP(11,13); CSWAPKP(14,16); CSWAPKP(15,17);
        CSWAPKP(18,20); CSWAPKP(19,21);
        // p=1
        CSWAPKP(0,1);  CSWAPKP(2,3);  CSWAPKP(4,5);  CSWAPKP(6,7);
        CSWAPKP(8,9);  CSWAPKP(10,11); CSWAPKP(12,13); CSWAPKP(14,15);
        CSWAPKP(16,17); CSWAPKP(18,19); CSWAPKP(20,21); CSWAPKP(22,23);
        CSWAPKP(1,16); CSWAPKP(3,18); CSWAPKP(5,20); CSWAPKP(7,22);
        CSWAPKP(1,8);  CSWAPKP(3,10); CSWAPKP(5,12); CSWAPKP(7,14);
        CSWAPKP(9,16); CSWAPKP(11,18); CSWAPKP(13,20); CSWAPKP(15,22);
        CSWAPKP(1,4);  CSWAPKP(3,6);  CSWAPKP(5,8);  CSWAPKP(7,10);
        CSWAPKP(9,12); CSWAPKP(11,14); CSWAPKP(13,16); CSWAPKP(15,18);
        CSWAPKP(17,20); CSWAPKP(19,22);
        CSWAPKP(1,2);  CSWAPKP(3,4);  CSWAPKP(5,6);  CSWAPKP(7,8);
        CSWAPKP(9,10); CSWAPKP(11,12); CSWAPKP(13,14); CSWAPKP(15,16);
        CSWAPKP(17,18); CSWAPKP(19,20); CSWAPKP(21,22);

        // ---- shoelace: v0-replication (registers, no LDS gather) ----
        // Invalid sorted positions (key >= 0x4E000000: 1e9/NaN mapped) take
        // v0's payload: terms j<k-1 normal, j=k-1 is the wrap
        // cross(v_{k-1}, v0), j>=k give cross(v0,v0)=0. k=0: all equal -> 0.
        const unsigned pv0 = pay[0];
        float X[NS + 1], Y[NS + 1];
#pragma unroll
        for (int j = 0; j < NS; j++) {
            const unsigned pv = (key[j] < 0x4E000000u) ? pay[j] : pv0;
            X[j] = (float)((int)(pv << 16) >> 16);   // sext low 16
            Y[j] = (float)((int)pv >> 16);
        }
        X[NS] = X[0]; Y[NS] = Y[0];
        // Independent pair terms into 3 rotating partials (breaks the float-add
        // dependency chain).
        float cr0 = 0.f, cr1 = 0.f, cr2 = 0.f;
#pragma unroll
        for (int j = 0; j < NS; j++) {
            const float t = X[j] * Y[j + 1] - Y[j] * X[j + 1];
            if ((j % 3) == 0) cr0 += t; else if ((j % 3) == 1) cr1 += t; else cr2 += t;
        }
        const float cr = (cr0 + cr1) + cr2;
        // Relative coords + closed loop => translation-invariant; uniform x128
        // scale folds into the final constant (0.5 / 128^2).
        const float area = fabsf(cr) * (0.5f / 16384.f);

        // ---- IoU + loss ----
        const float a1 = pw * ph, a2 = gw * gh;
        const float iou = fmaxf(area * rcpf(a1 + a2 - area), 1e-6f);
        loss = 1.f - iou + res;
    }

    // ---- block reduction: wave shuffle -> LDS -> one atomic per block ----
#pragma unroll
    for (int off = 32; off > 0; off >>= 1)
        loss += __shfl_down(loss, off, 64);
    if ((tid & 63) == 0) s_red[tid >> 6] = loss;
    __syncthreads();
    if (tid == 0) {
        float t = 0.f;
#pragma unroll
        for (int w = 0; w < BS / 64; w++) t += s_red[w];
        atomicAdd(out, t * inv_n);
    }
}

extern "C" void kernel_launch(void* const* d_in, const int* in_sizes, int n_in,
                              void* d_out, int out_size, void* d_ws, size_t ws_size,
                              hipStream_t stream)
{
    const float* pred = (const float*)d_in[0];
    const float* tgt  = (const float*)d_in[1];
    float* out = (float*)d_out;
    const int n = in_sizes[0] / 5;
    const int nblk = (n + BS - 1) / BS;

    hipMemsetAsync(out, 0, sizeof(float), stream);   // async on stream: capturable
    fpdiou_kernel<<<nblk, BS, 0, stream>>>(pred, tgt, out, n, 1.f / (float)n);
}

// Round 9
// 129.136 us; speedup vs baseline: 2.4337x; 2.4337x over previous
//
#include <hip/hip_runtime.h>

#define BS 256
#define NS 24   // candidate slots: 4 c1-corners, 4 c2-corners, 16 "intersections"

__device__ __forceinline__ float rcpf(float x) { return __builtin_amdgcn_rcpf(x); }

// One-instruction pack: round-nearest(clamp(x,-1,1)*32767) -> i16, y in high16.
__device__ __forceinline__ unsigned pk16(float x, float y) {
    unsigned r;
    asm("v_cvt_pknorm_i16_f32 %0, %1, %2" : "=v"(r) : "v"(x), "v"(y));
    return r;
}

// Key+payload compare-exchange, literal indices only (runtime indices ->
// scratch). 4 ops: key min/max + 2 payload cndmasks. Stable on key ties.
// NOTE (R8): this network holds ~100 live VGPRs; __launch_bounds__ minwaves
// MUST be <=4 (VGPR cap 128). The (256,8) clamp at 64 VGPR spilled the whole
// sort state to scratch: 682 MB writes/dispatch, 250 us. Never re-clamp.
#define CSWAPKP(A, B) do {                                        \
    const unsigned ka_ = key[A], kb_ = key[B];                    \
    const unsigned pa_ = pay[A], pb_ = pay[B];                    \
    const bool sw_ = (kb_ < ka_);                                 \
    key[A] = sw_ ? kb_ : ka_;  key[B] = sw_ ? ka_ : kb_;          \
    pay[A] = sw_ ? pb_ : pa_;  pay[B] = sw_ ? pa_ : pb_;          \
} while (0)

// (x,y) compare-exchange by x, literal indices
#define CSW2(x, y, I, J) do {                                     \
    const bool sw_ = (x[J] < x[I]);                               \
    const float xi_ = x[I], xj_ = x[J], yi_ = y[I], yj_ = y[J];   \
    x[I] = sw_ ? xj_ : xi_;  x[J] = sw_ ? xi_ : xj_;              \
    y[I] = sw_ ? yj_ : yi_;  y[J] = sw_ ? yi_ : yj_;              \
} while (0)

// NOTE (R4): BS=128 regressed 1.87x (2-wave blocks can't populate the CU).
// Keep BS=256. minwaves=4 -> VGPR cap 128: fits the ~80-100 live set, no spill.
__global__ __launch_bounds__(BS, 4)
void fpdiou_kernel(const float* __restrict__ pred, const float* __restrict__ tgt,
                   float* __restrict__ out, int n, float inv_n)
{
    __shared__ float s_red[BS / 64];

    const int tid = threadIdx.x;
    const int i = blockIdx.x * BS + tid;
    float loss = 0.f;

    if (i < n) {
        const float* pp = pred + (size_t)i * 5;
        const float* gg = tgt  + (size_t)i * 5;
        const float p0 = pp[0], p1 = pp[1], pw = pp[2], ph = pp[3], pa = pp[4];
        const float g0 = gg[0], g1 = gg[1], gw = gg[2], gh = gg[3], ga = gg[4];

        const float s1 = __sinf(pa), co1 = __cosf(pa);
        const float s2 = __sinf(ga), co2 = __cosf(ga);

        const float DX[4] = {0.5f, -0.5f, -0.5f, 0.5f};
        const float DY[4] = {0.5f,  0.5f, -0.5f, -0.5f};
        float c1x[4], c1y[4], c2x[4], c2y[4];
#pragma unroll
        for (int q = 0; q < 4; q++) {
            float dx = DX[q] * pw, dy = DY[q] * ph;
            c1x[q] = dx * co1 - dy * s1 + p0;
            c1y[q] = dx * s1 + dy * co1 + p1;
            dx = DX[q] * gw; dy = DY[q] * gh;
            c2x[q] = dx * co2 - dy * s2 + g0;
            c2y[q] = dx * s2 + dy * co2 + g1;
        }

        const float PKS = 128.f / 32767.f;   // pknorm scale: quantum = 1/128 px

        // ---- FPDIoU distance term: 5-comparator sort-by-x networks ----
        float res;
        {
            float px_[4] = {c1x[0], c1x[1], c1x[2], c1x[3]};
            float py_[4] = {c1y[0], c1y[1], c1y[2], c1y[3]};
            float gx_[4] = {c2x[0], c2x[1], c2x[2], c2x[3]};
            float gy_[4] = {c2y[0], c2y[1], c2y[2], c2y[3]};
            CSW2(px_, py_, 0, 1); CSW2(px_, py_, 2, 3);
            CSW2(px_, py_, 0, 2); CSW2(px_, py_, 1, 3); CSW2(px_, py_, 1, 2);
            CSW2(gx_, gy_, 0, 1); CSW2(gx_, gy_, 2, 3);
            CSW2(gx_, gy_, 0, 2); CSW2(gx_, gy_, 1, 3); CSW2(gx_, gy_, 1, 2);
            const float d0 = gx_[0] - px_[0];
            float d = 2.f * d0 * d0;
#pragma unroll
            for (int q = 1; q < 4; q++) {
                const float dxq = px_[q] - gx_[q];
                const float dyq = py_[q] - gy_[q];
                d += dxq * dxq + dyq * dyq;
            }
            res = d * (1.f / 4194304.f);
        }

        // ---- fill 24 slots: packed coords -> REGISTERS; validity bitmask ----
        unsigned pay[NS];
        unsigned vm = 0;
        float sx = 0.f, sy = 0.f;
        const float e = 1e-6f;

        // slots 0..3: c1 corners inside box2 (division-free threshold form)
        {
            const float ax = c2x[0], ay = c2y[0];
            const float abx = c2x[1] - ax, aby = c2y[1] - ay;
            const float adx = c2x[3] - ax, ady = c2y[3] - ay;
            const float dab = abx * abx + aby * aby;
            const float dad = adx * adx + ady * ady;
            const float lo_ab = -e * dab, hi_ab = (1.f + e) * dab;
            const float lo_ad = -e * dad, hi_ad = (1.f + e) * dad;
#pragma unroll
            for (int q = 0; q < 4; q++) {
                const float amx = c1x[q] - ax, amy = c1y[q] - ay;
                const float dot_ab = abx * amx + aby * amy;
                const float dot_ad = adx * amx + ady * amy;
                const bool m = (dot_ab > lo_ab) & (dot_ab < hi_ab)
                             & (dot_ad > lo_ad) & (dot_ad < hi_ad);
                pay[q] = pk16((c1x[q] - p0) * PKS, (c1y[q] - p1) * PKS);
                if (m) { vm |= 1u << q; sx += c1x[q]; sy += c1y[q]; }
            }
        }
        // slots 4..7: c2 corners inside box1
        {
            const float ax = c1x[0], ay = c1y[0];
            const float abx = c1x[1] - ax, aby = c1y[1] - ay;
            const float adx = c1x[3] - ax, ady = c1y[3] - ay;
            const float dab = abx * abx + aby * aby;
            const float dad = adx * adx + ady * ady;
            const float lo_ab = -e * dab, hi_ab = (1.f + e) * dab;
            const float lo_ad = -e * dad, hi_ad = (1.f + e) * dad;
#pragma unroll
            for (int q = 0; q < 4; q++) {
                const float amx = c2x[q] - ax, amy = c2y[q] - ay;
                const float dot_ab = abx * amx + aby * amy;
                const float dot_ad = adx * amx + ady * amy;
                const bool m = (dot_ab > lo_ab) & (dot_ab < hi_ab)
                             & (dot_ad > lo_ad) & (dot_ad < hi_ad);
                pay[4 + q] = pk16((c2x[q] - p0) * PKS, (c2y[q] - p1) * PKS);
                if (m) { vm |= 1u << (4 + q); sx += c2x[q]; sy += c2y[q]; }
            }
        }
        // slots 8..23: reference's quirky "intersections" (the reference's u has
        // a sign flip vs true segment params -- it accepts crossings with the
        // BACKWARD extension of c2 edges and rejects true crossings. This mask
        // emulates that exactly; do NOT replace with true geometry.)
        // ix,iy packed immediately -> no iix/iiy register arrays (VGPR budget).
#pragma unroll
        for (int a = 0; a < 4; a++) {
            const float x1 = c1x[a], y1 = c1y[a];
            const float ex = c1x[(a + 1) & 3] - x1, ey = c1y[(a + 1) & 3] - y1;
#pragma unroll
            for (int b = 0; b < 4; b++) {
                const float x3 = c2x[b], y3 = c2y[b];
                const float fx = c2x[(b + 1) & 3] - x3, fy = c2y[(b + 1) & 3] - y3;
                const float num = fy * ex - fx * ey;
                const float dx13 = x1 - x3, dy13 = y1 - y3;
                const float den_t = fx * dy13 - fy * dx13;
                const float den_u = ex * dy13 - ey * dx13;
                // t=den_t/num in (0,1) <=> den_t*num>0 && |den_t|<|num|;
                // u=-den_u/num in (0,1) <=> den_u*num<0 && |den_u|<|num|;
                // num==0 -> products +-0 -> strict cmps false (ref's t=-1 case).
                const bool m = (den_t * num > 0.f) & (fabsf(den_t) < fabsf(num))
                             & (den_u * num < 0.f) & (fabsf(den_u) < fabsf(num));
                const float t2 = den_t * rcpf(num + 1e-8f);   // reference quirk
                const float ix = fmaf(t2, ex, x1), iy = fmaf(t2, ey, y1);
                const int s = 8 + a * 4 + b;
                pay[s] = pk16((ix - p0) * PKS, (iy - p1) * PKS);
                if (m) { vm |= 1u << s; sx += ix; sy += iy; }
            }
        }

        // ---- keys from QUANTIZED payload (quantum units; angle order is ----
        // scale-invariant). ang = copysign(1 - dx/(|dx|+|dy|), dy) in [-2,2],
        // +4 -> [2,6] all positive => IEEE bits sort ascending as u32 directly.
        // Invalid -> 1e9f sorts after all valid. dx=dy=0 -> NaN key: sorts
        // last, fails the gather validity test => dropped (k<=2 cases give
        // area 0 under any order; k>=3 exact-coincidence is measure-zero).
        const int kq = __popc(vm);
        const float kf = (float)(kq > 0 ? kq : 1);
        const float rkf = rcpf(kf);
        const float oxq = (sx * rkf - p0) * 128.f;   // centroid, quantum units
        const float oyq = (sy * rkf - p1) * 128.f;
        unsigned key[NS];
#pragma unroll
        for (int s = 0; s < NS; s++) {
            const unsigned w = pay[s];
            const float dx = (float)((int)(w << 16) >> 16) - oxq;
            const float dy = (float)((int)w >> 16) - oyq;
            const float sa = fabsf(dx) + fabsf(dy);
            const float m1 = fmaf(-dx, rcpf(sa), 1.f);       // [0,2]
            float a4 = copysignf(m1, dy) + 4.f;              // [2,6]
            a4 = ((vm >> s) & 1u) ? a4 : 1e9f;               // invalid -> back
            key[s] = (__float_as_uint(a4) & 0xFFFFFFE0u) | (unsigned)s;
        }

        // ---- Batcher merge-exchange network, n=24 (127 comparators), ----
        // key + payload carried in registers.
        // p=16
        CSWAPKP(0,16); CSWAPKP(1,17); CSWAPKP(2,18); CSWAPKP(3,19);
        CSWAPKP(4,20); CSWAPKP(5,21); CSWAPKP(6,22); CSWAPKP(7,23);
        // p=8
        CSWAPKP(0,8);  CSWAPKP(1,9);  CSWAPKP(2,10); CSWAPKP(3,11);
        CSWAPKP(4,12); CSWAPKP(5,13); CSWAPKP(6,14); CSWAPKP(7,15);
        CSWAPKP(8,16); CSWAPKP(9,17); CSWAPKP(10,18); CSWAPKP(11,19);
        CSWAPKP(12,20); CSWAPKP(13,21); CSWAPKP(14,22); CSWAPKP(15,23);
        // p=4
        CSWAPKP(0,4);  CSWAPKP(1,5);  CSWAPKP(2,6);  CSWAPKP(3,7);
        CSWAPKP(8,12); CSWAPKP(9,13); CSWAPKP(10,14); CSWAPKP(11,15);
        CSWAPKP(16,20); CSWAPKP(17,21); CSWAPKP(18,22); CSWAPKP(19,23);
        CSWAPKP(4,16); CSWAPKP(5,17); CSWAPKP(6,18); CSWAPKP(7,19);
        CSWAPKP(4,8);  CSWAPKP(5,9);  CSWAPKP(6,10); CSWAPKP(7,11);
        CSWAPKP(12,16); CSWAPKP(13,17); CSWAPKP(14,18); CSWAPKP(15,19);
        // p=2
        CSWAPKP(0,2);  CSWAPKP(1,3);  CSWAPKP(4,6);  CSWAPKP(5,7);
        CSWAPKP(8,10); CSWAPKP(9,11); CSWAPKP(12,14); CSWAPKP(13,15);
        CSWAPKP(16,18); CSWAPKP(17,19); CSWAPKP(20,22); CSWAPKP(21,23);
        CSWAPKP(2,16); CSWAPKP(3,17); CSWAPKP(6,20); CSWAPKP(7,21);
        CSWAPKP(2,8);  CSWAPKP(3,9);  CSWAPKP(6,12); CSWAPKP(7,13);
        CSWAPKP(10,16); CSWAPKP(11,17); CSWAPKP(14,20); CSWAPKP(15,21);
        CSWAPKP(2,4);  CSWAPKP(3,5);  CSWAPKP(6,8);  CSWAPKP(7,9);
        CSWAPKP(10,12); CSWAPKP(11,13); CSWAPKP(14,16); CSWAPKP(15,17);
        CSWAPKP(18,20); CSWAPKP(19,21);
        // p=1
        CSWAPKP(0,1);  CSWAPKP(2,3);  CSWAPKP(4,5);  CSWAPKP(6,7);
        CSWAPKP(8,9);  CSWAPKP(10,11); CSWAPKP(12,13); CSWAPKP(14,15);
        CSWAPKP(16,17); CSWAPKP(18,19); CSWAPKP(20,21); CSWAPKP(22,23);
        CSWAPKP(1,16); CSWAPKP(3,18); CSWAPKP(5,20); CSWAPKP(7,22);
        CSWAPKP(1,8);  CSWAPKP(3,10); CSWAPKP(5,12); CSWAPKP(7,14);
        CSWAPKP(9,16); CSWAPKP(11,18); CSWAPKP(13,20); CSWAPKP(15,22);
        CSWAPKP(1,4);  CSWAPKP(3,6);  CSWAPKP(5,8);  CSWAPKP(7,10);
        CSWAPKP(9,12); CSWAPKP(11,14); CSWAPKP(13,16); CSWAPKP(15,18);
        CSWAPKP(17,20); CSWAPKP(19,22);
        CSWAPKP(1,2);  CSWAPKP(3,4);  CSWAPKP(5,6);  CSWAPKP(7,8);
        CSWAPKP(9,10); CSWAPKP(11,12); CSWAPKP(13,14); CSWAPKP(15,16);
        CSWAPKP(17,18); CSWAPKP(19,20); CSWAPKP(21,22);

        // ---- rolling shoelace: v0-replication, unpack-on-the-fly ----
        // Invalid sorted positions (key >= 0x4E000000: 1e9/NaN mapped) take
        // v0's payload: terms j<k-1 normal, j=k-1 is the wrap
        // cross(v_{k-1}, v0), j>=k give cross(v0,v0)=0. k=0: all equal -> 0.
        // Rolling prev/cur keeps the live set small (no X[25]/Y[25] arrays).
        const unsigned pv0 = pay[0];
        const float fx0 = (float)((int)(pv0 << 16) >> 16);
        const float fy0 = (float)((int)pv0 >> 16);
        float xp = fx0, yp = fy0;
        float cr0 = 0.f, cr1 = 0.f, cr2 = 0.f;
#pragma unroll
        for (int j = 1; j < NS; j++) {
            const unsigned pv = (key[j] < 0x4E000000u) ? pay[j] : pv0;
            const float xc = (float)((int)(pv << 16) >> 16);
            const float yc = (float)((int)pv >> 16);
            const float t = xp * yc - yp * xc;
            if ((j % 3) == 0) cr0 += t; else if ((j % 3) == 1) cr1 += t; else cr2 += t;
            xp = xc; yp = yc;
        }
        const float cr = (cr0 + cr1) + (cr2 + (xp * fy0 - yp * fx0));  // wrap
        // Relative coords + closed loop => translation-invariant; uniform x128
        // scale folds into the final constant (0.5 / 128^2).
        const float area = fabsf(cr) * (0.5f / 16384.f);

        // ---- IoU + loss ----
        const float a1 = pw * ph, a2 = gw * gh;
        const float iou = fmaxf(area * rcpf(a1 + a2 - area), 1e-6f);
        loss = 1.f - iou + res;
    }

    // ---- block reduction: wave shuffle -> LDS -> one atomic per block ----
#pragma unroll
    for (int off = 32; off > 0; off >>= 1)
        loss += __shfl_down(loss, off, 64);
    if ((tid & 63) == 0) s_red[tid >> 6] = loss;
    __syncthreads();
    if (tid == 0) {
        float t = 0.f;
#pragma unroll
        for (int w = 0; w < BS / 64; w++) t += s_red[w];
        atomicAdd(out, t * inv_n);
    }
}

extern "C" void kernel_launch(void* const* d_in, const int* in_sizes, int n_in,
                              void* d_out, int out_size, void* d_ws, size_t ws_size,
                              hipStream_t stream)
{
    const float* pred = (const float*)d_in[0];
    const float* tgt  = (const float*)d_in[1];
    float* out = (float*)d_out;
    const int n = in_sizes[0] / 5;
    const int nblk = (n + BS - 1) / BS;

    hipMemsetAsync(out, 0, sizeof(float), stream);   // async on stream: capturable
    fpdiou_kernel<<<nblk, BS, 0, stream>>>(pred, tgt, out, n, 1.f / (float)n);
}